// Round 1
// baseline (477.374 us; speedup 1.0000x reference)
//
#include <hip/hip_runtime.h>

#define NNODES 50000
#define NEDGES 800000
#define IN_C   512
#define HID_C  128
#define OUT_C  64

// ---------------- graph prep ----------------

__global__ void init_kernel(float* __restrict__ deg, int* __restrict__ counts, int n) {
  int i = blockIdx.x * blockDim.x + threadIdx.x;
  if (i < n) { deg[i] = 1.0f; counts[i] = 1; }   // self-loop: weight 1, one CSR slot
}

__global__ void deg_count_kernel(const int* __restrict__ ei, const float* __restrict__ ew,
                                 float* __restrict__ deg, int* __restrict__ counts, int nE) {
  int e = blockIdx.x * blockDim.x + threadIdx.x;
  if (e < nE) {
    int c = ei[nE + e];               // edge_index[1][e] (destination)
    atomicAdd(&deg[c], ew[e]);
    atomicAdd(&counts[c], 1);
  }
}

__global__ void dinv_kernel(float* __restrict__ deg, int n) {
  int i = blockIdx.x * blockDim.x + threadIdx.x;
  if (i < n) { float d = deg[i]; deg[i] = d > 0.f ? rsqrtf(d) : 0.f; }
}

// single-block chunked exclusive scan over counts -> offs[0..n]
__global__ void __launch_bounds__(1024) scan_kernel(const int* __restrict__ counts,
                                                    int* __restrict__ offs, int n) {
  const int T = 1024;
  int t = threadIdx.x;
  int chunk = (n + T - 1) / T;
  int s0 = t * chunk; if (s0 > n) s0 = n;
  int s1 = s0 + chunk; if (s1 > n) s1 = n;
  int sum = 0;
  for (int i = s0; i < s1; ++i) sum += counts[i];
  __shared__ int lds[T];
  lds[t] = sum;
  __syncthreads();
  for (int off = 1; off < T; off <<= 1) {
    int v = (t >= off) ? lds[t - off] : 0;
    __syncthreads();
    lds[t] += v;
    __syncthreads();
  }
  int prefix = (t > 0) ? lds[t - 1] : 0;   // exclusive prefix of this chunk
  for (int i = s0; i < s1; ++i) { offs[i] = prefix; prefix += counts[i]; }
  if (t == T - 1) offs[n] = lds[T - 1];
}

__global__ void copy_int_kernel(const int* __restrict__ src, int* __restrict__ dst, int n) {
  int i = blockIdx.x * blockDim.x + threadIdx.x;
  if (i < n) dst[i] = src[i];
}

// fill CSR (sorted by destination): rows[] = source node, norms[] = dinv[r]*w*dinv[c]
__global__ void fill_kernel(const int* __restrict__ ei, const float* __restrict__ ew,
                            const float* __restrict__ dinv, int* __restrict__ cursor,
                            int* __restrict__ rows, float* __restrict__ norms,
                            int nE, int nN) {
  int i = blockIdx.x * blockDim.x + threadIdx.x;
  if (i < nN) {                       // self-loop of node i
    float di = dinv[i];
    int pos = atomicAdd(&cursor[i], 1);
    rows[pos] = i;
    norms[pos] = di * di;
  } else if (i < nN + nE) {
    int e = i - nN;
    int r = ei[e], c = ei[nE + e];
    float w = dinv[r] * ew[e] * dinv[c];
    int pos = atomicAdd(&cursor[c], 1);
    rows[pos] = r;
    norms[pos] = w;
  }
}

// ---------------- f32 SGEMM: Y[M,N] = X[M,K] @ W[K,N] ----------------
// BM=128, BK=16, TM=8; block = 256 threads = 16x16 micro-grid; TN = N/16
template <int K, int N, int TN>
__global__ void __launch_bounds__(256) gemm_kernel(const float* __restrict__ X,
                                                   const float* __restrict__ W,
                                                   float* __restrict__ Y, int M) {
  constexpr int BM = 128, BK = 16, TM = 8;
  constexpr int APAD = 4, BPAD = 4;
  __shared__ float Ast[BK][BM + APAD];   // transposed A tile
  __shared__ float Bs[BK][N + BPAD];
  int tid = threadIdx.x;
  int tn = tid & 15;    // 0..15 (col group)
  int tm = tid >> 4;    // 0..15 (row group)
  int block_row = blockIdx.x * BM;

  float acc[TM][TN];
#pragma unroll
  for (int i = 0; i < TM; ++i)
#pragma unroll
    for (int j = 0; j < TN; ++j) acc[i][j] = 0.f;

  constexpr int A_PER_T = (BM * BK / 4) / 256;   // 2
  constexpr int B_PER_T = (BK * N / 4) / 256;    // 2 (N=128) or 1 (N=64)

  for (int k0 = 0; k0 < K; k0 += BK) {
    // A tile: global float4 loads (coalesced), store transposed to LDS
#pragma unroll
    for (int l = 0; l < A_PER_T; ++l) {
      int s = l * 256 + tid;
      int r = s >> 2;
      int kc = (s & 3) * 4;
      int gr = block_row + r;
      float4 v = make_float4(0.f, 0.f, 0.f, 0.f);
      if (gr < M) v = *reinterpret_cast<const float4*>(&X[(size_t)gr * K + k0 + kc]);
      Ast[kc + 0][r] = v.x; Ast[kc + 1][r] = v.y;
      Ast[kc + 2][r] = v.z; Ast[kc + 3][r] = v.w;
    }
    // B tile: row-major vector copy
#pragma unroll
    for (int l = 0; l < B_PER_T; ++l) {
      int s = l * 256 + tid;
      int br = s / (N / 4);
      int bc = (s % (N / 4)) * 4;
      float4 v = *reinterpret_cast<const float4*>(&W[(size_t)(k0 + br) * N + bc]);
      *reinterpret_cast<float4*>(&Bs[br][bc]) = v;
    }
    __syncthreads();
#pragma unroll
    for (int kk = 0; kk < BK; ++kk) {
      float a[TM], bv[TN];
      *reinterpret_cast<float4*>(&a[0]) = *reinterpret_cast<const float4*>(&Ast[kk][tm * TM]);
      *reinterpret_cast<float4*>(&a[4]) = *reinterpret_cast<const float4*>(&Ast[kk][tm * TM + 4]);
#pragma unroll
      for (int j = 0; j < TN; j += 4)
        *reinterpret_cast<float4*>(&bv[j]) = *reinterpret_cast<const float4*>(&Bs[kk][tn * TN + j]);
#pragma unroll
      for (int i = 0; i < TM; ++i)
#pragma unroll
        for (int j = 0; j < TN; ++j)
          acc[i][j] = fmaf(a[i], bv[j], acc[i][j]);
    }
    __syncthreads();
  }
#pragma unroll
  for (int i = 0; i < TM; ++i) {
    int gr = block_row + tm * TM + i;
    if (gr < M) {
#pragma unroll
      for (int j = 0; j < TN; j += 4) {
        float4 v = make_float4(acc[i][j], acc[i][j + 1], acc[i][j + 2], acc[i][j + 3]);
        *reinterpret_cast<float4*>(&Y[(size_t)gr * N + tn * TN + j]) = v;
      }
    }
  }
}

// ---------------- CSR aggregation: out[n] = bias + sum_e norm[e]*feat[rows[e]] ----------------
template <int F, bool RELU>
__global__ void agg_kernel(const float* __restrict__ feat,
                           const int* __restrict__ offs, const int* __restrict__ rows,
                           const float* __restrict__ norms, const float* __restrict__ bias,
                           float* __restrict__ out, int n) {
  int node = blockIdx.x;
  int f = threadIdx.x;
  int e0 = offs[node], e1 = offs[node + 1];
  float acc = bias[f];
  for (int e = e0; e < e1; ++e) {
    int r = rows[e];            // uniform across lanes -> broadcast load
    float w = norms[e];
    acc = fmaf(w, feat[(size_t)r * F + f], acc);
  }
  if (RELU) acc = fmaxf(acc, 0.f);
  out[(size_t)node * F + f] = acc;
}

// ---------------- launch ----------------

extern "C" void kernel_launch(void* const* d_in, const int* in_sizes, int n_in,
                              void* d_out, int out_size, void* d_ws, size_t ws_size,
                              hipStream_t stream) {
  const float* x  = (const float*)d_in[0];
  const int*   ei = (const int*)d_in[1];     // [2, E] int
  const float* ew = (const float*)d_in[2];
  const float* W1 = (const float*)d_in[3];
  const float* b1 = (const float*)d_in[4];
  const float* W2 = (const float*)d_in[5];
  const float* b2 = (const float*)d_in[6];
  float* out = (float*)d_out;

  const int N = NNODES, E = NEDGES, EP = NNODES + NEDGES;

  char* p = (char*)d_ws;
  auto alloc = [&](size_t bytes) { char* r = p; p += (bytes + 255) & ~(size_t)255; return r; };
  float* deg    = (float*)alloc((size_t)N * 4);        // becomes dinv in-place
  int*   counts = (int*)  alloc((size_t)N * 4);
  int*   offs   = (int*)  alloc((size_t)(N + 1) * 4);
  int*   cursor = (int*)  alloc((size_t)N * 4);
  int*   rows   = (int*)  alloc((size_t)EP * 4);
  float* norms  = (float*)alloc((size_t)EP * 4);
  float* xw     = (float*)alloc((size_t)N * HID_C * 4); // layer1 pre-agg; reused as h2
  float* h      = (float*)alloc((size_t)N * HID_C * 4); // layer1 output

  init_kernel<<<(N + 255) / 256, 256, 0, stream>>>(deg, counts, N);
  deg_count_kernel<<<(E + 255) / 256, 256, 0, stream>>>(ei, ew, deg, counts, E);
  dinv_kernel<<<(N + 255) / 256, 256, 0, stream>>>(deg, N);
  scan_kernel<<<1, 1024, 0, stream>>>(counts, offs, N);
  copy_int_kernel<<<(N + 255) / 256, 256, 0, stream>>>(offs, cursor, N);
  fill_kernel<<<(EP + 255) / 256, 256, 0, stream>>>(ei, ew, deg, cursor, rows, norms, E, N);

  // layer 1: xw = x @ W1 ; h = relu(agg(xw) + b1)
  gemm_kernel<IN_C, HID_C, 8><<<(N + 127) / 128, 256, 0, stream>>>(x, W1, xw, N);
  agg_kernel<HID_C, true><<<N, HID_C, 0, stream>>>(xw, offs, rows, norms, b1, h, N);

  // layer 2: h2 = h @ W2 ; out = agg(h2) + b2
  gemm_kernel<HID_C, OUT_C, 4><<<(N + 127) / 128, 256, 0, stream>>>(h, W2, xw, N);
  agg_kernel<OUT_C, false><<<N, OUT_C, 0, stream>>>(xw, offs, rows, norms, b2, out, N);
}

// Round 2
// 445.452 us; speedup vs baseline: 1.0717x; 1.0717x over previous
//
#include <hip/hip_runtime.h>

#define NNODES 50000
#define NEDGES 800000
#define IN_C   512
#define HID_C  128
#define OUT_C  64

// ---------------- graph prep ----------------

__global__ void init_kernel(float* __restrict__ deg, int* __restrict__ counts, int n) {
  int i = blockIdx.x * blockDim.x + threadIdx.x;
  if (i < n) { deg[i] = 1.0f; counts[i] = 1; }   // self-loop: weight 1, one CSR slot
}

__global__ void deg_count_kernel(const int* __restrict__ ei, const float* __restrict__ ew,
                                 float* __restrict__ deg, int* __restrict__ counts, int nE) {
  int e = blockIdx.x * blockDim.x + threadIdx.x;
  if (e < nE) {
    int c = ei[nE + e];               // edge_index[1][e] (destination)
    atomicAdd(&deg[c], ew[e]);
    atomicAdd(&counts[c], 1);
  }
}

__global__ void dinv_kernel(float* __restrict__ deg, int n) {
  int i = blockIdx.x * blockDim.x + threadIdx.x;
  if (i < n) { float d = deg[i]; deg[i] = d > 0.f ? rsqrtf(d) : 0.f; }
}

// single-block chunked exclusive scan over counts -> offs[0..n]
__global__ void __launch_bounds__(1024) scan_kernel(const int* __restrict__ counts,
                                                    int* __restrict__ offs, int n) {
  const int T = 1024;
  int t = threadIdx.x;
  int chunk = (n + T - 1) / T;
  int s0 = t * chunk; if (s0 > n) s0 = n;
  int s1 = s0 + chunk; if (s1 > n) s1 = n;
  int sum = 0;
  for (int i = s0; i < s1; ++i) sum += counts[i];
  __shared__ int lds[T];
  lds[t] = sum;
  __syncthreads();
  for (int off = 1; off < T; off <<= 1) {
    int v = (t >= off) ? lds[t - off] : 0;
    __syncthreads();
    lds[t] += v;
    __syncthreads();
  }
  int prefix = (t > 0) ? lds[t - 1] : 0;   // exclusive prefix of this chunk
  for (int i = s0; i < s1; ++i) { offs[i] = prefix; prefix += counts[i]; }
  if (t == T - 1) offs[n] = lds[T - 1];
}

__global__ void copy_int_kernel(const int* __restrict__ src, int* __restrict__ dst, int n) {
  int i = blockIdx.x * blockDim.x + threadIdx.x;
  if (i < n) dst[i] = src[i];
}

// fill CSR (sorted by destination): rows[] = source node, norms[] = dinv[r]*w*dinv[c]
__global__ void fill_kernel(const int* __restrict__ ei, const float* __restrict__ ew,
                            const float* __restrict__ dinv, int* __restrict__ cursor,
                            int* __restrict__ rows, float* __restrict__ norms,
                            int nE, int nN) {
  int i = blockIdx.x * blockDim.x + threadIdx.x;
  if (i < nN) {                       // self-loop of node i
    float di = dinv[i];
    int pos = atomicAdd(&cursor[i], 1);
    rows[pos] = i;
    norms[pos] = di * di;
  } else if (i < nN + nE) {
    int e = i - nN;
    int r = ei[e], c = ei[nE + e];
    float w = dinv[r] * ew[e] * dinv[c];
    int pos = atomicAdd(&cursor[c], 1);
    rows[pos] = r;
    norms[pos] = w;
  }
}

// ---------------- f32 SGEMM: Y[M,N] = X[M,K] @ W[K,N] ----------------
// BM=64, BK=16, TM=4; 256 threads = 16(tm) x 16(tn); cols split into 64-wide
// halves read at 16B lane stride (2-way bank alias = free) instead of 32B (4-way).
template <int K, int N>   // N multiple of 64
__global__ void __launch_bounds__(256) gemm_kernel(const float* __restrict__ X,
                                                   const float* __restrict__ W,
                                                   float* __restrict__ Y, int M) {
  constexpr int BM = 64, BK = 16, TM = 4;
  constexpr int NH = N / 64;              // 64-col halves (2 for N=128, 1 for N=64)
  __shared__ float Ast[BK][BM + 4];       // transposed A tile, stride 68 (272B, 16B-aligned)
  __shared__ float Bs[BK][N + 8];         // stride N+8 (16B-aligned rows)
  int tid = threadIdx.x;
  int tn = tid & 15;    // col group
  int tm = tid >> 4;    // row group
  int block_row = blockIdx.x * BM;

  float acc[TM][NH][4];
#pragma unroll
  for (int i = 0; i < TM; ++i)
#pragma unroll
    for (int h = 0; h < NH; ++h)
#pragma unroll
      for (int j = 0; j < 4; ++j) acc[i][h][j] = 0.f;

  constexpr int B_PER_T = (BK * N / 4) / 256;   // 2 (N=128) or 1 (N=64)

  for (int k0 = 0; k0 < K; k0 += BK) {
    // A tile: one float4 per thread, stored transposed
    {
      int r = tid >> 2;            // 0..63
      int kc = (tid & 3) * 4;      // 0,4,8,12
      int gr = block_row + r;
      float4 v = make_float4(0.f, 0.f, 0.f, 0.f);
      if (gr < M) v = *reinterpret_cast<const float4*>(&X[(size_t)gr * K + k0 + kc]);
      Ast[kc + 0][r] = v.x; Ast[kc + 1][r] = v.y;
      Ast[kc + 2][r] = v.z; Ast[kc + 3][r] = v.w;
    }
    // B tile: row-major float4 copy
#pragma unroll
    for (int l = 0; l < B_PER_T; ++l) {
      int s = l * 256 + tid;
      int br = s / (N / 4);
      int bc = (s % (N / 4)) * 4;
      float4 v = *reinterpret_cast<const float4*>(&W[(size_t)(k0 + br) * N + bc]);
      *reinterpret_cast<float4*>(&Bs[br][bc]) = v;
    }
    __syncthreads();
#pragma unroll
    for (int kk = 0; kk < BK; ++kk) {
      float a[TM];
      *reinterpret_cast<float4*>(&a[0]) = *reinterpret_cast<const float4*>(&Ast[kk][tm * TM]);
      float bv[NH][4];
#pragma unroll
      for (int h = 0; h < NH; ++h)
        *reinterpret_cast<float4*>(&bv[h][0]) =
            *reinterpret_cast<const float4*>(&Bs[kk][h * 64 + tn * 4]);
#pragma unroll
      for (int i = 0; i < TM; ++i)
#pragma unroll
        for (int h = 0; h < NH; ++h)
#pragma unroll
          for (int j = 0; j < 4; ++j)
            acc[i][h][j] = fmaf(a[i], bv[h][j], acc[i][h][j]);
    }
    __syncthreads();
  }
#pragma unroll
  for (int i = 0; i < TM; ++i) {
    int gr = block_row + tm * TM + i;
    if (gr < M) {
#pragma unroll
      for (int h = 0; h < NH; ++h) {
        float4 v = make_float4(acc[i][h][0], acc[i][h][1], acc[i][h][2], acc[i][h][3]);
        *reinterpret_cast<float4*>(&Y[(size_t)gr * N + h * 64 + tn * 4]) = v;
      }
    }
  }
}

// ---------------- CSR aggregation: out[n] = bias + sum_e norm[e]*feat[rows[e]] ----------------
// one wave per node, 4 nodes per 256-thread block; lane covers F/64 features
template <int F, bool RELU>
__global__ void __launch_bounds__(256) agg_kernel(const float* __restrict__ feat,
                                                  const int* __restrict__ offs,
                                                  const int* __restrict__ rows,
                                                  const float* __restrict__ norms,
                                                  const float* __restrict__ bias,
                                                  float* __restrict__ out, int n) {
  constexpr int VEC = F / 64;   // 2 (F=128) or 1 (F=64)
  int wid = threadIdx.x >> 6;
  int lane = threadIdx.x & 63;
  int node = blockIdx.x * 4 + wid;
  if (node >= n) return;
  int e0 = offs[node], e1 = offs[node + 1];

  if constexpr (VEC == 2) {
    float2 acc = *reinterpret_cast<const float2*>(&bias[lane * 2]);
    int e = e0;
    for (; e + 1 < e1; e += 2) {
      int r0 = rows[e], r1 = rows[e + 1];
      float w0 = norms[e], w1 = norms[e + 1];
      float2 f0 = *reinterpret_cast<const float2*>(&feat[(size_t)r0 * F + lane * 2]);
      float2 f1 = *reinterpret_cast<const float2*>(&feat[(size_t)r1 * F + lane * 2]);
      acc.x = fmaf(w0, f0.x, acc.x); acc.y = fmaf(w0, f0.y, acc.y);
      acc.x = fmaf(w1, f1.x, acc.x); acc.y = fmaf(w1, f1.y, acc.y);
    }
    if (e < e1) {
      int r0 = rows[e]; float w0 = norms[e];
      float2 f0 = *reinterpret_cast<const float2*>(&feat[(size_t)r0 * F + lane * 2]);
      acc.x = fmaf(w0, f0.x, acc.x); acc.y = fmaf(w0, f0.y, acc.y);
    }
    if (RELU) { acc.x = fmaxf(acc.x, 0.f); acc.y = fmaxf(acc.y, 0.f); }
    *reinterpret_cast<float2*>(&out[(size_t)node * F + lane * 2]) = acc;
  } else {
    float acc = bias[lane];
    int e = e0;
    for (; e + 1 < e1; e += 2) {
      int r0 = rows[e], r1 = rows[e + 1];
      float w0 = norms[e], w1 = norms[e + 1];
      float f0 = feat[(size_t)r0 * F + lane];
      float f1 = feat[(size_t)r1 * F + lane];
      acc = fmaf(w0, f0, acc);
      acc = fmaf(w1, f1, acc);
    }
    if (e < e1) {
      acc = fmaf(norms[e], feat[(size_t)rows[e] * F + lane], acc);
    }
    if (RELU) acc = fmaxf(acc, 0.f);
    out[(size_t)node * F + lane] = acc;
  }
}

// ---------------- launch ----------------

extern "C" void kernel_launch(void* const* d_in, const int* in_sizes, int n_in,
                              void* d_out, int out_size, void* d_ws, size_t ws_size,
                              hipStream_t stream) {
  const float* x  = (const float*)d_in[0];
  const int*   ei = (const int*)d_in[1];     // [2, E] int
  const float* ew = (const float*)d_in[2];
  const float* W1 = (const float*)d_in[3];
  const float* b1 = (const float*)d_in[4];
  const float* W2 = (const float*)d_in[5];
  const float* b2 = (const float*)d_in[6];
  float* out = (float*)d_out;

  const int N = NNODES, E = NEDGES, EP = NNODES + NEDGES;

  char* p = (char*)d_ws;
  auto alloc = [&](size_t bytes) { char* r = p; p += (bytes + 255) & ~(size_t)255; return r; };
  float* deg    = (float*)alloc((size_t)N * 4);        // becomes dinv in-place
  int*   counts = (int*)  alloc((size_t)N * 4);
  int*   offs   = (int*)  alloc((size_t)(N + 1) * 4);
  int*   cursor = (int*)  alloc((size_t)N * 4);
  int*   rows   = (int*)  alloc((size_t)EP * 4);
  float* norms  = (float*)alloc((size_t)EP * 4);
  float* xw     = (float*)alloc((size_t)N * HID_C * 4); // layer1 pre-agg; reused as h2
  float* h      = (float*)alloc((size_t)N * HID_C * 4); // layer1 output

  init_kernel<<<(N + 255) / 256, 256, 0, stream>>>(deg, counts, N);
  deg_count_kernel<<<(E + 255) / 256, 256, 0, stream>>>(ei, ew, deg, counts, E);
  dinv_kernel<<<(N + 255) / 256, 256, 0, stream>>>(deg, N);
  scan_kernel<<<1, 1024, 0, stream>>>(counts, offs, N);
  copy_int_kernel<<<(N + 255) / 256, 256, 0, stream>>>(offs, cursor, N);
  fill_kernel<<<(EP + 255) / 256, 256, 0, stream>>>(ei, ew, deg, cursor, rows, norms, E, N);

  // layer 1: xw = x @ W1 ; h = relu(agg(xw) + b1)
  gemm_kernel<IN_C, HID_C><<<(N + 63) / 64, 256, 0, stream>>>(x, W1, xw, N);
  agg_kernel<HID_C, true><<<(N + 3) / 4, 256, 0, stream>>>(xw, offs, rows, norms, b1, h, N);

  // layer 2: h2 = h @ W2 ; out = agg(h2) + b2
  gemm_kernel<HID_C, OUT_C><<<(N + 63) / 64, 256, 0, stream>>>(h, W2, xw, N);
  agg_kernel<OUT_C, false><<<(N + 3) / 4, 256, 0, stream>>>(xw, offs, rows, norms, b2, out, N);
}

// Round 3
// 439.085 us; speedup vs baseline: 1.0872x; 1.0145x over previous
//
#include <hip/hip_runtime.h>

#define NNODES 50000
#define NEDGES 800000
#define IN_C   512
#define HID_C  128
#define OUT_C  64

typedef float  f32x4  __attribute__((ext_vector_type(4)));
typedef __bf16 bf16x8 __attribute__((ext_vector_type(8)));
typedef short  short8 __attribute__((ext_vector_type(8)));

// ---------------- graph prep ----------------

__global__ void init_kernel(float* __restrict__ deg, int* __restrict__ counts, int n) {
  int i = blockIdx.x * blockDim.x + threadIdx.x;
  if (i < n) { deg[i] = 1.0f; counts[i] = 1; }   // self-loop: weight 1, one CSR slot
}

__global__ void deg_count_kernel(const int* __restrict__ ei, const float* __restrict__ ew,
                                 float* __restrict__ deg, int* __restrict__ counts, int nE) {
  int e = blockIdx.x * blockDim.x + threadIdx.x;
  if (e < nE) {
    int c = ei[nE + e];               // edge_index[1][e] (destination)
    atomicAdd(&deg[c], ew[e]);
    atomicAdd(&counts[c], 1);
  }
}

__global__ void dinv_kernel(float* __restrict__ deg, int n) {
  int i = blockIdx.x * blockDim.x + threadIdx.x;
  if (i < n) { float d = deg[i]; deg[i] = d > 0.f ? rsqrtf(d) : 0.f; }
}

// single-block chunked exclusive scan over counts -> offs[0..n]
__global__ void __launch_bounds__(1024) scan_kernel(const int* __restrict__ counts,
                                                    int* __restrict__ offs, int n) {
  const int T = 1024;
  int t = threadIdx.x;
  int chunk = (n + T - 1) / T;
  int s0 = t * chunk; if (s0 > n) s0 = n;
  int s1 = s0 + chunk; if (s1 > n) s1 = n;
  int sum = 0;
  for (int i = s0; i < s1; ++i) sum += counts[i];
  __shared__ int lds[T];
  lds[t] = sum;
  __syncthreads();
  for (int off = 1; off < T; off <<= 1) {
    int v = (t >= off) ? lds[t - off] : 0;
    __syncthreads();
    lds[t] += v;
    __syncthreads();
  }
  int prefix = (t > 0) ? lds[t - 1] : 0;   // exclusive prefix of this chunk
  for (int i = s0; i < s1; ++i) { offs[i] = prefix; prefix += counts[i]; }
  if (t == T - 1) offs[n] = lds[T - 1];
}

__global__ void copy_int_kernel(const int* __restrict__ src, int* __restrict__ dst, int n) {
  int i = blockIdx.x * blockDim.x + threadIdx.x;
  if (i < n) dst[i] = src[i];
}

// fill CSR (sorted by destination): rows[] = source node, norms[] = dinv[r]*w*dinv[c]
__global__ void fill_kernel(const int* __restrict__ ei, const float* __restrict__ ew,
                            const float* __restrict__ dinv, int* __restrict__ cursor,
                            int* __restrict__ rows, float* __restrict__ norms,
                            int nE, int nN) {
  int i = blockIdx.x * blockDim.x + threadIdx.x;
  if (i < nN) {                       // self-loop of node i
    float di = dinv[i];
    int pos = atomicAdd(&cursor[i], 1);
    rows[pos] = i;
    norms[pos] = di * di;
  } else if (i < nN + nE) {
    int e = i - nN;
    int r = ei[e], c = ei[nE + e];
    float w = dinv[r] * ew[e] * dinv[c];
    int pos = atomicAdd(&cursor[c], 1);
    rows[pos] = r;
    norms[pos] = w;
  }
}

// ---------------- W split+transpose: W[K][N] f32 -> Wt hi/lo [N][K] bf16 ----------------

__global__ void wsplit_kernel(const float* __restrict__ W, unsigned short* __restrict__ Th,
                              unsigned short* __restrict__ Tl, int K, int N) {
  int id = blockIdx.x * blockDim.x + threadIdx.x;
  if (id >= K * N) return;
  int k = id % K, n = id / K;           // consecutive id -> consecutive k -> coalesced writes
  float f = W[(size_t)k * N + n];
  __bf16 hb = (__bf16)f;
  float hf = (float)hb;
  __bf16 lb = (__bf16)(f - hf);
  Th[id] = __builtin_bit_cast(unsigned short, hb);
  Tl[id] = __builtin_bit_cast(unsigned short, lb);
}

// ---------------- split-bf16 MFMA GEMM: Y[M,N] = X[M,K] @ W[K,N] ----------------
// LDS-free. Wt hi/lo are W^T in bf16 (L2-resident, shared by all blocks).
// Block: BM=64 rows x N cols; waves = 2*WN (wave tile 32x64). N = WN*64.
// Split trick: Y ~= Xh@Wh + Xh@Wl + Xl@Wh  (Xl@Wl ~ 2^-18 relative, dropped)
template <int K, int WN>
__global__ void __launch_bounds__(64 * 2 * WN) gemm_mfma_kernel(
    const float* __restrict__ X, const unsigned short* __restrict__ Bth,
    const unsigned short* __restrict__ Btl, float* __restrict__ Y, int M) {
  constexpr int N = WN * 64;
  int tid = threadIdx.x;
  int lane = tid & 63, wid = tid >> 6;
  int wr = wid / WN, wc = wid % WN;     // wr 0..1, wc 0..WN-1
  int row0 = blockIdx.x * 64 + wr * 32;
  int rlo = lane & 15;                  // row/col within fragment
  int khi = lane >> 4;                  // k-group (0..3), 8 k each

  f32x4 acc[2][4] = {};

#pragma unroll 4
  for (int ks = 0; ks < K / 32; ++ks) {
    int kb = ks * 32 + khi * 8;
    // A fragments: rows row0 + m*16 + rlo, 8 contiguous k; convert f32 -> bf16 hi/lo
    bf16x8 ah[2], al[2];
#pragma unroll
    for (int m = 0; m < 2; ++m) {
      int row = row0 + m * 16 + rlo;
      row = row < M ? row : M - 1;      // clamp (results discarded at store)
      const float* src = X + (size_t)row * K + kb;
      float4 v0 = *reinterpret_cast<const float4*>(src);
      float4 v1 = *reinterpret_cast<const float4*>(src + 4);
      float f[8] = {v0.x, v0.y, v0.z, v0.w, v1.x, v1.y, v1.z, v1.w};
#pragma unroll
      for (int i = 0; i < 8; ++i) {
        __bf16 h = (__bf16)f[i];
        ah[m][i] = h;
        al[m][i] = (__bf16)(f[i] - (float)h);
      }
    }
    // B fragments: col = wc*64 + n*16 + rlo, 8 contiguous k from W^T (bf16)
    bf16x8 bh[4], bl[4];
#pragma unroll
    for (int n = 0; n < 4; ++n) {
      size_t off = (size_t)(wc * 64 + n * 16 + rlo) * K + kb;
      bh[n] = __builtin_bit_cast(bf16x8, *reinterpret_cast<const short8*>(Bth + off));
      bl[n] = __builtin_bit_cast(bf16x8, *reinterpret_cast<const short8*>(Btl + off));
    }
#pragma unroll
    for (int m = 0; m < 2; ++m)
#pragma unroll
      for (int n = 0; n < 4; ++n) {
        acc[m][n] = __builtin_amdgcn_mfma_f32_16x16x32_bf16(ah[m], bh[n], acc[m][n], 0, 0, 0);
        acc[m][n] = __builtin_amdgcn_mfma_f32_16x16x32_bf16(ah[m], bl[n], acc[m][n], 0, 0, 0);
        acc[m][n] = __builtin_amdgcn_mfma_f32_16x16x32_bf16(al[m], bh[n], acc[m][n], 0, 0, 0);
      }
  }
  // C/D layout: col = lane&15, row = (lane>>4)*4 + reg  [m89-verified]
#pragma unroll
  for (int m = 0; m < 2; ++m)
#pragma unroll
    for (int j = 0; j < 4; ++j) {
      int row = row0 + m * 16 + khi * 4 + j;
      if (row < M) {
#pragma unroll
        for (int n = 0; n < 4; ++n)
          Y[(size_t)row * N + wc * 64 + n * 16 + rlo] = acc[m][n][j];
      }
    }
}

// ---------------- CSR aggregation: out[n] = bias + sum_e norm[e]*feat[rows[e]] ----------------
// one wave per node, 4 nodes per 256-thread block; lane covers F/64 features
template <int F, bool RELU>
__global__ void __launch_bounds__(256) agg_kernel(const float* __restrict__ feat,
                                                  const int* __restrict__ offs,
                                                  const int* __restrict__ rows,
                                                  const float* __restrict__ norms,
                                                  const float* __restrict__ bias,
                                                  float* __restrict__ out, int n) {
  constexpr int VEC = F / 64;   // 2 (F=128) or 1 (F=64)
  int wid = threadIdx.x >> 6;
  int lane = threadIdx.x & 63;
  int node = blockIdx.x * 4 + wid;
  if (node >= n) return;
  int e0 = offs[node], e1 = offs[node + 1];

  if constexpr (VEC == 2) {
    float2 acc = *reinterpret_cast<const float2*>(&bias[lane * 2]);
    int e = e0;
    for (; e + 1 < e1; e += 2) {
      int r0 = rows[e], r1 = rows[e + 1];
      float w0 = norms[e], w1 = norms[e + 1];
      float2 f0 = *reinterpret_cast<const float2*>(&feat[(size_t)r0 * F + lane * 2]);
      float2 f1 = *reinterpret_cast<const float2*>(&feat[(size_t)r1 * F + lane * 2]);
      acc.x = fmaf(w0, f0.x, acc.x); acc.y = fmaf(w0, f0.y, acc.y);
      acc.x = fmaf(w1, f1.x, acc.x); acc.y = fmaf(w1, f1.y, acc.y);
    }
    if (e < e1) {
      int r0 = rows[e]; float w0 = norms[e];
      float2 f0 = *reinterpret_cast<const float2*>(&feat[(size_t)r0 * F + lane * 2]);
      acc.x = fmaf(w0, f0.x, acc.x); acc.y = fmaf(w0, f0.y, acc.y);
    }
    if (RELU) { acc.x = fmaxf(acc.x, 0.f); acc.y = fmaxf(acc.y, 0.f); }
    *reinterpret_cast<float2*>(&out[(size_t)node * F + lane * 2]) = acc;
  } else {
    float acc = bias[lane];
    int e = e0;
    for (; e + 1 < e1; e += 2) {
      int r0 = rows[e], r1 = rows[e + 1];
      float w0 = norms[e], w1 = norms[e + 1];
      float f0 = feat[(size_t)r0 * F + lane];
      float f1 = feat[(size_t)r1 * F + lane];
      acc = fmaf(w0, f0, acc);
      acc = fmaf(w1, f1, acc);
    }
    if (e < e1) {
      acc = fmaf(norms[e], feat[(size_t)rows[e] * F + lane], acc);
    }
    if (RELU) acc = fmaxf(acc, 0.f);
    out[(size_t)node * F + lane] = acc;
  }
}

// ---------------- launch ----------------

extern "C" void kernel_launch(void* const* d_in, const int* in_sizes, int n_in,
                              void* d_out, int out_size, void* d_ws, size_t ws_size,
                              hipStream_t stream) {
  const float* x  = (const float*)d_in[0];
  const int*   ei = (const int*)d_in[1];     // [2, E] int
  const float* ew = (const float*)d_in[2];
  const float* W1 = (const float*)d_in[3];
  const float* b1 = (const float*)d_in[4];
  const float* W2 = (const float*)d_in[5];
  const float* b2 = (const float*)d_in[6];
  float* out = (float*)d_out;

  const int N = NNODES, E = NEDGES, EP = NNODES + NEDGES;

  char* p = (char*)d_ws;
  auto alloc = [&](size_t bytes) { char* r = p; p += (bytes + 255) & ~(size_t)255; return r; };
  float* deg    = (float*)alloc((size_t)N * 4);        // becomes dinv in-place
  int*   counts = (int*)  alloc((size_t)N * 4);
  int*   offs   = (int*)  alloc((size_t)(N + 1) * 4);
  int*   cursor = (int*)  alloc((size_t)N * 4);
  int*   rows   = (int*)  alloc((size_t)EP * 4);
  float* norms  = (float*)alloc((size_t)EP * 4);
  float* xw     = (float*)alloc((size_t)N * HID_C * 4); // layer1 pre-agg; reused as h2
  float* h      = (float*)alloc((size_t)N * HID_C * 4); // layer1 output
  unsigned short* W1th = (unsigned short*)alloc((size_t)IN_C * HID_C * 2);
  unsigned short* W1tl = (unsigned short*)alloc((size_t)IN_C * HID_C * 2);
  unsigned short* W2th = (unsigned short*)alloc((size_t)HID_C * OUT_C * 2);
  unsigned short* W2tl = (unsigned short*)alloc((size_t)HID_C * OUT_C * 2);

  init_kernel<<<(N + 255) / 256, 256, 0, stream>>>(deg, counts, N);
  deg_count_kernel<<<(E + 255) / 256, 256, 0, stream>>>(ei, ew, deg, counts, E);
  dinv_kernel<<<(N + 255) / 256, 256, 0, stream>>>(deg, N);
  scan_kernel<<<1, 1024, 0, stream>>>(counts, offs, N);
  copy_int_kernel<<<(N + 255) / 256, 256, 0, stream>>>(offs, cursor, N);
  fill_kernel<<<(EP + 255) / 256, 256, 0, stream>>>(ei, ew, deg, cursor, rows, norms, E, N);
  wsplit_kernel<<<(IN_C * HID_C + 255) / 256, 256, 0, stream>>>(W1, W1th, W1tl, IN_C, HID_C);
  wsplit_kernel<<<(HID_C * OUT_C + 255) / 256, 256, 0, stream>>>(W2, W2th, W2tl, HID_C, OUT_C);

  const int gemm_grid = (N + 63) / 64;
  // layer 1: xw = x @ W1 ; h = relu(agg(xw) + b1)
  gemm_mfma_kernel<IN_C, 2><<<gemm_grid, 256, 0, stream>>>(x, W1th, W1tl, xw, N);
  agg_kernel<HID_C, true><<<(N + 3) / 4, 256, 0, stream>>>(xw, offs, rows, norms, b1, h, N);

  // layer 2: h2 = h @ W2 ; out = agg(h2) + b2
  gemm_mfma_kernel<HID_C, 1><<<gemm_grid, 128, 0, stream>>>(h, W2th, W2tl, xw, N);
  agg_kernel<OUT_C, false><<<(N + 3) / 4, 256, 0, stream>>>(xw, offs, rows, norms, b2, out, N);
}